// Round 17
// baseline (118.070 us; speedup 1.0000x reference)
//
#include <hip/hip_runtime.h>

// Problem constants
constexpr int B_ = 32, C_ = 64, H_ = 64, W_ = 64, K_ = 1024;
constexpr int NTOT = B_ * C_ * H_ * W_;          // 8388608 elements of input1/quantized
constexpr int NSP  = B_ * H_ * W_;               // 131072 spatial positions
// d_out float offsets: [0]=loss, [1..32]=input2_KL, [33..33+NTOT)=quantized(BCHW),
// [OFF_ENC .. OFF_ENC+NSP*K)=encodings
constexpr int OFF_Q   = 33;
constexpr int OFF_ENC = OFF_Q + NTOT;            // 8388641 (byte 33554564 == 4 mod 64)
constexpr long long ENC_ELEMS = (long long)NSP * K_;   // 134217728 (2^27)
// (OFF_ENC + 15)*4 == 0 mod 64: fill starts 64B-LINE-aligned.
// Head (row 0, cols 0..14) and tail (last row, col 1023) patched in vq_fin.
constexpr int ENC_HEAD = 15;
constexpr int ENC_NQ = (int)((ENC_ELEMS - ENC_HEAD - 1) / 4);   // 33554428 quads
constexpr int ENC_BLOCKS = (ENC_NQ + 255) / 256;                // 131072 blocks

constexpr int MAIN_BLOCKS  = NSP / 64;                          // 2048 blocks
constexpr int TOTAL_BLOCKS = ENC_BLOCKS + MAIN_BLOCKS;          // 133120

typedef float v4f __attribute__((ext_vector_type(4)));

// Fused kernel, ENC FIRST / MAIN LAST (R16 structure, best = 106.5 us).
// Delta vs R16: the main path's streaming traffic is ALSO nontemporal —
// NT loads on input1 (read once) and NT stores on quantized (written once,
// never re-read) — so the gather phase no longer allocates L2 lines that
// compete with the 537 MB NT store stream during the overlap window.
// Weight and x_tilde stay cached (genuinely reused).
__global__ __launch_bounds__(256) void vq_fused(const float* __restrict__ input1,
                                                const int*   __restrict__ x_tilde,
                                                const float* __restrict__ weight,
                                                float* __restrict__ out,  // d_out base
                                                float* __restrict__ ws) { // d_ws partials
    const int bid = blockIdx.x;
    if (bid < ENC_BLOCKS) {
        // ---- encodings fill path (one-shot: one 16B NT store per thread) ----
        const int b  = bid;
        const int qi = b * 256 + threadIdx.x;
        if (qi >= ENC_NQ) return;             // 4 idle threads in the last block
        const int t0 = x_tilde[b];
        const int t1 = x_tilde[(b + 1 < NSP) ? b + 1 : NSP - 1];
        const int col0 = ENC_HEAD + (threadIdx.x << 2);        // 15..1035 rel. row b
        v4f v;
        #pragma unroll
        for (int j = 0; j < 4; ++j) {
            const int col = col0 + j;
            ((float*)&v)[j] = (col < 1024) ? ((t0 == col) ? 1.f : 0.f)
                                           : ((t1 == col - 1024) ? 1.f : 0.f);
        }
        __builtin_nontemporal_store(v,
            reinterpret_cast<v4f*>(out + OFF_ENC + ENC_HEAD + (qi << 2)));
        return;
    }

    // ---- quantized + loss path (transposed gather, 4-way channel split) ----
    const int mq  = bid - ENC_BLOCKS;                // 0..MAIN_BLOCKS-1
    const int tid = threadIdx.x;
    const int n   = mq * 64 + (tid & 63);            // [0, NSP)
    const int cq  = tid >> 6;                        // 0..3 -> channels 16cq..16cq+15
    const int b   = n >> 12;                         // H*W = 4096
    const int hw  = n & 4095;
    const int t   = x_tilde[n];
    const float* __restrict__ wrow = weight + (t << 6) + (cq << 4);
    const float* __restrict__ xin  = input1 + (b << 18) + (cq << 16) + hw;
    float* __restrict__ qout = out + OFF_Q + (b << 18) + (cq << 16) + hw;

    const float4 w0 = *reinterpret_cast<const float4*>(wrow);
    const float4 w1 = *reinterpret_cast<const float4*>(wrow + 4);
    const float4 w2 = *reinterpret_cast<const float4*>(wrow + 8);
    const float4 w3 = *reinterpret_cast<const float4*>(wrow + 12);
    const float wv[16] = {w0.x, w0.y, w0.z, w0.w, w1.x, w1.y, w1.z, w1.w,
                          w2.x, w2.y, w2.z, w2.w, w3.x, w3.y, w3.z, w3.w};
    float local = 0.f;
    #pragma unroll
    for (int j = 0; j < 16; ++j) {
        const float x = __builtin_nontemporal_load(xin + (j << 12));
        const float d = wv[j] - x;
        __builtin_nontemporal_store(x + d, qout + (j << 12));  // x + (q - x)
        local += d * d;
    }

    // per-wave reduce; one plain store per wave -> ws[4*mq + wid]; no barrier
    for (int o = 32; o > 0; o >>= 1) local += __shfl_down(local, o);
    if ((tid & 63) == 0) {
        ws[(mq << 2) | (tid >> 6)] = local;
    }
}

// Finalize: reduce 8192 per-wave partials -> loss, input2_KL passthrough, and
// the 16 edge elements the line-aligned fill skipped.
__global__ __launch_bounds__(256) void vq_fin(const int* __restrict__ x_tilde,
                                              const float* __restrict__ ws,
                                              const float* __restrict__ kl,
                                              float* __restrict__ out) {
    const int tid = threadIdx.x;
    float local = 0.f;
    #pragma unroll
    for (int k = 0; k < 32; ++k) local += ws[tid + (k << 8)];
    for (int o = 32; o > 0; o >>= 1) local += __shfl_down(local, o);
    __shared__ float sm[4];
    if ((tid & 63) == 0) sm[tid >> 6] = local;
    __syncthreads();
    if (tid == 0) out[0] = 1.25f * (sm[0] + sm[1] + sm[2] + sm[3]) / (float)NTOT;
    if (tid >= 64 && tid < 96) out[1 + tid - 64] = kl[tid - 64];
    if (tid == 96) {
        const int t0 = x_tilde[0];
        #pragma unroll
        for (int j = 0; j < ENC_HEAD; ++j)
            out[OFF_ENC + j] = (t0 == j) ? 1.f : 0.f;      // row 0, cols 0..14
        const int tl = x_tilde[NSP - 1];
        out[OFF_ENC + (int)ENC_ELEMS - 1] = (tl == 1023) ? 1.f : 0.f;
    }
}

extern "C" void kernel_launch(void* const* d_in, const int* in_sizes, int n_in,
                              void* d_out, int out_size, void* d_ws, size_t ws_size,
                              hipStream_t stream) {
    const float* input1 = (const float*)d_in[0];
    const float* kl     = (const float*)d_in[1];
    const float* weight = (const float*)d_in[2];
    const int*   x_til  = (const int*)d_in[3];
    float* out = (float*)d_out;
    float* ws  = (float*)d_ws;

    vq_fused<<<TOTAL_BLOCKS, 256, 0, stream>>>(input1, x_til, weight, out, ws);
    vq_fin<<<1, 256, 0, stream>>>(x_til, ws, kl, out);
}

// Round 18
// 106.328 us; speedup vs baseline: 1.1104x; 1.1104x over previous
//
#include <hip/hip_runtime.h>

// Problem constants
constexpr int B_ = 32, C_ = 64, H_ = 64, W_ = 64, K_ = 1024;
constexpr int NTOT = B_ * C_ * H_ * W_;          // 8388608 elements of input1/quantized
constexpr int NSP  = B_ * H_ * W_;               // 131072 spatial positions
// d_out float offsets: [0]=loss, [1..32]=input2_KL, [33..33+NTOT)=quantized(BCHW),
// [OFF_ENC .. OFF_ENC+NSP*K)=encodings
constexpr int OFF_Q   = 33;
constexpr int OFF_ENC = OFF_Q + NTOT;            // 8388641 (byte 33554564 == 4 mod 64)
constexpr long long ENC_ELEMS = (long long)NSP * K_;   // 134217728 (2^27)
// (OFF_ENC + 15)*4 == 0 mod 64: fill starts 64B-LINE-aligned.
// Head (row 0, cols 0..14) and tail (last row, col 1023) patched in vq_fin.
constexpr int ENC_HEAD = 15;
constexpr int ENC_NQ = (int)((ENC_ELEMS - ENC_HEAD - 1) / 4);   // 33554428 quads
constexpr int ENC_BLOCKS = (ENC_NQ + 255) / 256;                // 131072 blocks

constexpr int MAIN_BLOCKS  = NSP / 64;                          // 2048 blocks
constexpr int TOTAL_BLOCKS = ENC_BLOCKS + MAIN_BLOCKS;          // 133120

typedef float v4f __attribute__((ext_vector_type(4)));

// Fused kernel, ENC FIRST / MAIN LAST — exact R16 configuration (measured best,
// 106.5 us). NT stores ONLY on the 16B-aligned full-line one-hot stream (R16's
// +16 us win); main path stays fully cached (R17 proved NT there costs ~11 us:
// scalar NT stores defeat L2 write-combining, NT loads forfeit wave line reuse).
__global__ __launch_bounds__(256) void vq_fused(const float* __restrict__ input1,
                                                const int*   __restrict__ x_tilde,
                                                const float* __restrict__ weight,
                                                float* __restrict__ out,  // d_out base
                                                float* __restrict__ ws) { // d_ws partials
    const int bid = blockIdx.x;
    if (bid < ENC_BLOCKS) {
        // ---- encodings fill path (one-shot: one 16B NT store per thread) ----
        const int b  = bid;
        const int qi = b * 256 + threadIdx.x;
        if (qi >= ENC_NQ) return;             // 4 idle threads in the last block
        const int t0 = x_tilde[b];
        const int t1 = x_tilde[(b + 1 < NSP) ? b + 1 : NSP - 1];
        const int col0 = ENC_HEAD + (threadIdx.x << 2);        // 15..1035 rel. row b
        v4f v;
        #pragma unroll
        for (int j = 0; j < 4; ++j) {
            const int col = col0 + j;
            ((float*)&v)[j] = (col < 1024) ? ((t0 == col) ? 1.f : 0.f)
                                           : ((t1 == col - 1024) ? 1.f : 0.f);
        }
        __builtin_nontemporal_store(v,
            reinterpret_cast<v4f*>(out + OFF_ENC + ENC_HEAD + (qi << 2)));
        return;
    }

    // ---- quantized + loss path (transposed gather, 4-way channel split) ----
    const int mq  = bid - ENC_BLOCKS;                // 0..MAIN_BLOCKS-1
    const int tid = threadIdx.x;
    const int n   = mq * 64 + (tid & 63);            // [0, NSP)
    const int cq  = tid >> 6;                        // 0..3 -> channels 16cq..16cq+15
    const int b   = n >> 12;                         // H*W = 4096
    const int hw  = n & 4095;
    const int t   = x_tilde[n];
    const float* __restrict__ wrow = weight + (t << 6) + (cq << 4);
    const float* __restrict__ xin  = input1 + (b << 18) + (cq << 16) + hw;
    float* __restrict__ qout = out + OFF_Q + (b << 18) + (cq << 16) + hw;

    const float4 w0 = *reinterpret_cast<const float4*>(wrow);
    const float4 w1 = *reinterpret_cast<const float4*>(wrow + 4);
    const float4 w2 = *reinterpret_cast<const float4*>(wrow + 8);
    const float4 w3 = *reinterpret_cast<const float4*>(wrow + 12);
    const float wv[16] = {w0.x, w0.y, w0.z, w0.w, w1.x, w1.y, w1.z, w1.w,
                          w2.x, w2.y, w2.z, w2.w, w3.x, w3.y, w3.z, w3.w};
    float local = 0.f;
    #pragma unroll
    for (int j = 0; j < 16; ++j) {
        const float x = xin[j << 12];
        const float d = wv[j] - x;
        qout[j << 12] = x + d;       // straight-through: x + (q - x)
        local += d * d;
    }

    // per-wave reduce; one plain store per wave -> ws[4*mq + wid]; no barrier
    for (int o = 32; o > 0; o >>= 1) local += __shfl_down(local, o);
    if ((tid & 63) == 0) {
        ws[(mq << 2) | (tid >> 6)] = local;
    }
}

// Finalize: reduce 8192 per-wave partials -> loss, input2_KL passthrough, and
// the 16 edge elements the line-aligned fill skipped.
__global__ __launch_bounds__(256) void vq_fin(const int* __restrict__ x_tilde,
                                              const float* __restrict__ ws,
                                              const float* __restrict__ kl,
                                              float* __restrict__ out) {
    const int tid = threadIdx.x;
    float local = 0.f;
    #pragma unroll
    for (int k = 0; k < 32; ++k) local += ws[tid + (k << 8)];
    for (int o = 32; o > 0; o >>= 1) local += __shfl_down(local, o);
    __shared__ float sm[4];
    if ((tid & 63) == 0) sm[tid >> 6] = local;
    __syncthreads();
    if (tid == 0) out[0] = 1.25f * (sm[0] + sm[1] + sm[2] + sm[3]) / (float)NTOT;
    if (tid >= 64 && tid < 96) out[1 + tid - 64] = kl[tid - 64];
    if (tid == 96) {
        const int t0 = x_tilde[0];
        #pragma unroll
        for (int j = 0; j < ENC_HEAD; ++j)
            out[OFF_ENC + j] = (t0 == j) ? 1.f : 0.f;      // row 0, cols 0..14
        const int tl = x_tilde[NSP - 1];
        out[OFF_ENC + (int)ENC_ELEMS - 1] = (tl == 1023) ? 1.f : 0.f;
    }
}

extern "C" void kernel_launch(void* const* d_in, const int* in_sizes, int n_in,
                              void* d_out, int out_size, void* d_ws, size_t ws_size,
                              hipStream_t stream) {
    const float* input1 = (const float*)d_in[0];
    const float* kl     = (const float*)d_in[1];
    const float* weight = (const float*)d_in[2];
    const int*   x_til  = (const int*)d_in[3];
    float* out = (float*)d_out;
    float* ws  = (float*)d_ws;

    vq_fused<<<TOTAL_BLOCKS, 256, 0, stream>>>(input1, x_til, weight, out, ws);
    vq_fin<<<1, 256, 0, stream>>>(x_til, ws, kl, out);
}